// Round 6
// baseline (456.967 us; speedup 1.0000x reference)
//
#include <hip/hip_runtime.h>

// Causal single-head attention, B=8, N=2048, D=1024, fp32 in/out, bf16 MFMA compute.
//
// Pipeline (all on `stream`):
//   1. cast_f32_bf16:      x (fp32) -> xb (bf16)
//   2. transpose_cast_w:   Wq/Wk/Wv (fp32 KxN) -> WT (bf16 NxK)
//   3. gemm_bt<0>: Q = xb·Wq (bf16); gemm_bt<0>: K = xb·Wk; gemm_bt<1>: Vt = (xb·Wv)^T
//   4. memset rowsum=0; gemm_bt<2>: E = exp(scale·Q·K^T) bf16, causal-masked, lower
//      128x128 tiles only; epilogue reduces per-row sums (4x shfl_xor over column
//      lanes) and atomicAdds into rowsum[b*SEQ+row].  No max-subtraction: scaled
//      scores ~N(0,1), max ~5.5 -> exp safe in fp32/bf16.
//   5. gemm_bt<3>: out = (E·V) * (1/rowsum[row]) via Vt; K-loop causally limited;
//      by reversed so heavy (long-K) blocks dispatch first (kills the tail).
//   R6: rowsum moved from PV inner loop (32 VALU/k-step) to E epilogue atomics.

typedef unsigned short u16;
typedef __bf16 bf16x8 __attribute__((ext_vector_type(8)));
typedef float f32x4 __attribute__((ext_vector_type(4)));
typedef unsigned short u16x8 __attribute__((ext_vector_type(8)));

static constexpr int BATCH = 8;
static constexpr int SEQ = 2048;
static constexpr int DIM = 1024;

static constexpr size_t SZ_XB = (size_t)BATCH * SEQ * DIM * 2;  // 32 MiB
static constexpr size_t SZ_W  = (size_t)DIM * DIM * 2;          // 2 MiB
static constexpr size_t OFF_XB  = 0;
static constexpr size_t OFF_WQT = OFF_XB + SZ_XB;
static constexpr size_t OFF_WKT = OFF_WQT + SZ_W;
static constexpr size_t OFF_WVT = OFF_WKT + SZ_W;
static constexpr size_t OFF_Q   = OFF_WVT + SZ_W;
static constexpr size_t OFF_K   = OFF_Q + SZ_XB;
static constexpr size_t OFF_VT  = OFF_K + SZ_XB;
static constexpr size_t OFF_E   = OFF_VT + SZ_XB;               // bf16 8x2048x2048 = 64 MiB
static constexpr size_t OFF_RS  = OFF_E + (size_t)BATCH * SEQ * SEQ * 2;  // fp32 16384
// total ~198 MiB + 64 KB

__device__ __forceinline__ u16 f2b(float f) {
  unsigned u = __builtin_bit_cast(unsigned, f);
  u += 0x7fffu + ((u >> 16) & 1u);
  return (u16)(u >> 16);
}

__device__ __forceinline__ void gload16(const u16* g, u16* l) {
  __builtin_amdgcn_global_load_lds((__attribute__((address_space(1))) void*)g,
                                   (__attribute__((address_space(3))) void*)l, 16, 0, 0);
}

__global__ __launch_bounds__(256) void cast_f32_bf16(const float* __restrict__ in,
                                                     u16* __restrict__ out) {
  const size_t i = ((size_t)blockIdx.x * 256 + threadIdx.x) * 8;
  float4 a = *(const float4*)(in + i);
  float4 b = *(const float4*)(in + i + 4);
  u16x8 o;
  o[0] = f2b(a.x); o[1] = f2b(a.y); o[2] = f2b(a.z); o[3] = f2b(a.w);
  o[4] = f2b(b.x); o[5] = f2b(b.y); o[6] = f2b(b.z); o[7] = f2b(b.w);
  *reinterpret_cast<u16x8*>(out + i) = o;
}

__global__ __launch_bounds__(256) void transpose_cast_w(const float* __restrict__ W,
                                                        u16* __restrict__ WT) {
  __shared__ float t[32][33];
  const int k0 = blockIdx.x * 32, n0 = blockIdx.y * 32;
  const int tx = threadIdx.x, ty = threadIdx.y;
#pragma unroll
  for (int dy = 0; dy < 32; dy += 8)
    t[ty + dy][tx] = W[(size_t)(k0 + ty + dy) * DIM + n0 + tx];
  __syncthreads();
#pragma unroll
  for (int dy = 0; dy < 32; dy += 8)
    WT[(size_t)(n0 + ty + dy) * DIM + k0 + tx] = f2b(t[tx][ty + dy]);
}

// C = A(bf16 MxK rm) * B^T-given (Bt: N x K rm). 128x128 tile, 4 waves, 4x4 16x16x32 MFMA.
// MODE 0: C bf16 row-major
// MODE 1: C bf16 transposed per batch: C[b][col][n], b=row>>11, n=row&2047 (Vt build)
// MODE 2: C bf16 = exp(acc*scale) causal-masked; lower tiles only (bx<=by);
//         epilogue: per-row sum of exp -> atomicAdd Rsum[bz*SEQ+row]
// MODE 3: C fp32 = acc * (1/Rsum[bz*SEQ+row]); K-loop limited to (by+1)*128;
//         by reversed (heavy blocks first)
template <int MODE>
__global__ __launch_bounds__(256, 2) void gemm_bt(
    const u16* __restrict__ A, size_t sA, int lda,
    const u16* __restrict__ Bt, size_t sB, int ldb,
    void* __restrict__ C, size_t sC, int ldc,
    int Kdim, float scale, float* __restrict__ Rsum) {
  const int bx = blockIdx.x, bz = blockIdx.z;
  const int by = (MODE == 3) ? (gridDim.y - 1 - blockIdx.y) : blockIdx.y;
  if (MODE == 2 && bx > by) return;
  const u16* Ab = A + (size_t)bz * sA;
  const u16* Bb = Bt + (size_t)bz * sB;
  const int rowTile = by * 128, colTile = bx * 128;
  int kmax = Kdim;
  if (MODE == 3) {
    int km = (by + 1) * 128;
    if (km < kmax) kmax = km;
  }

  __shared__ __align__(16) u16 As[128 * 32];
  __shared__ __align__(16) u16 Bs[128 * 32];

  const int tid = threadIdx.x;
  const int w = tid >> 6, l = tid & 63;
  const int wr = (w >> 1) * 64, wc = (w & 1) * 64;
  const int lr = l & 15, quad = l >> 4;

  f32x4 acc[4][4];
#pragma unroll
  for (int i = 0; i < 4; ++i)
#pragma unroll
    for (int j = 0; j < 4; ++j) acc[i][j] = (f32x4){0.f, 0.f, 0.f, 0.f};

  const int srow = w * 16 + (l >> 2);
  const int scol = (l & 3) * 8;
  const u16* gA0 = Ab + (size_t)(rowTile + srow) * lda + scol;
  const u16* gA1 = gA0 + (size_t)64 * lda;
  const u16* gB0 = Bb + (size_t)(colTile + srow) * ldb + scol;
  const u16* gB1 = gB0 + (size_t)64 * ldb;
  u16* lA0 = &As[(w * 16) * 32];
  u16* lA1 = &As[(64 + w * 16) * 32];
  u16* lB0 = &Bs[(w * 16) * 32];
  u16* lB1 = &Bs[(64 + w * 16) * 32];

  for (int k0 = 0; k0 < kmax; k0 += 32) {
    __syncthreads();
    gload16(gA0 + k0, lA0);
    gload16(gA1 + k0, lA1);
    gload16(gB0 + k0, lB0);
    gload16(gB1 + k0, lB1);
    __syncthreads();
    bf16x8 af[4], bfr[4];
#pragma unroll
    for (int mi = 0; mi < 4; ++mi)
      af[mi] = *reinterpret_cast<const bf16x8*>(&As[(wr + mi * 16 + lr) * 32 + quad * 8]);
#pragma unroll
    for (int ni = 0; ni < 4; ++ni)
      bfr[ni] = *reinterpret_cast<const bf16x8*>(&Bs[(wc + ni * 16 + lr) * 32 + quad * 8]);
#pragma unroll
    for (int mi = 0; mi < 4; ++mi)
#pragma unroll
      for (int ni = 0; ni < 4; ++ni)
        acc[mi][ni] =
            __builtin_amdgcn_mfma_f32_16x16x32_bf16(af[mi], bfr[ni], acc[mi][ni], 0, 0, 0);
  }

  // C/D layout: col = lane&15, row = (lane>>4)*4 + reg  [m89-verified]
  const int orow0 = rowTile + wr + quad * 4;
  const int ocol0 = colTile + wc + lr;
#pragma unroll
  for (int mi = 0; mi < 4; ++mi) {
    float rp[4] = {0.f, 0.f, 0.f, 0.f};  // MODE 2: row partials over this lane's 4 cols
    float linv[4];
    if (MODE == 3) {
#pragma unroll
      for (int r = 0; r < 4; ++r)
        linv[r] = 1.f / Rsum[(size_t)bz * SEQ + orow0 + mi * 16 + r];
    }
#pragma unroll
    for (int ni = 0; ni < 4; ++ni) {
      const int colg = ocol0 + ni * 16;
#pragma unroll
      for (int r = 0; r < 4; ++r) {
        const int rowg = orow0 + mi * 16 + r;
        const float v = acc[mi][ni][r];
        if (MODE == 0) {
          ((u16*)C)[(size_t)bz * sC + (size_t)rowg * ldc + colg] = f2b(v);
        } else if (MODE == 1) {
          const int bb = rowg >> 11, nn = rowg & (SEQ - 1);
          ((u16*)C)[(size_t)bb * sC + (size_t)colg * ldc + nn] = f2b(v);
        } else if (MODE == 2) {
          const float e = (colg <= rowg) ? __expf(v * scale) : 0.f;
          rp[r] += e;
          ((u16*)C)[(size_t)bz * sC + (size_t)rowg * ldc + colg] = f2b(e);
        } else {
          ((float*)C)[(size_t)bz * sC + (size_t)rowg * ldc + colg] = v * linv[r];
        }
      }
    }
    if (MODE == 2) {
      // reduce over the 16 column-lanes (lanes differing in low 4 bits share a row)
#pragma unroll
      for (int r = 0; r < 4; ++r) {
        rp[r] += __shfl_xor(rp[r], 1);
        rp[r] += __shfl_xor(rp[r], 2);
        rp[r] += __shfl_xor(rp[r], 4);
        rp[r] += __shfl_xor(rp[r], 8);
      }
      if (lr == 0) {
#pragma unroll
        for (int r = 0; r < 4; ++r)
          atomicAdd(&Rsum[(size_t)bz * SEQ + orow0 + mi * 16 + r], rp[r]);
      }
    }
  }
}

extern "C" void kernel_launch(void* const* d_in, const int* in_sizes, int n_in,
                              void* d_out, int out_size, void* d_ws, size_t ws_size,
                              hipStream_t stream) {
  const float* x = (const float*)d_in[0];
  const float* Wq = (const float*)d_in[1];
  const float* Wk = (const float*)d_in[2];
  const float* Wv = (const float*)d_in[3];
  float* out = (float*)d_out;
  char* ws = (char*)d_ws;

  u16* xb = (u16*)(ws + OFF_XB);
  u16* wqT = (u16*)(ws + OFF_WQT);
  u16* wkT = (u16*)(ws + OFF_WKT);
  u16* wvT = (u16*)(ws + OFF_WVT);
  u16* qb = (u16*)(ws + OFF_Q);
  u16* kb = (u16*)(ws + OFF_K);
  u16* vt = (u16*)(ws + OFF_VT);
  u16* eb = (u16*)(ws + OFF_E);
  float* rs = (float*)(ws + OFF_RS);

  const int total = BATCH * SEQ * DIM;
  cast_f32_bf16<<<total / (256 * 8), 256, 0, stream>>>(x, xb);
  transpose_cast_w<<<dim3(32, 32), dim3(32, 8), 0, stream>>>(Wq, wqT);
  transpose_cast_w<<<dim3(32, 32), dim3(32, 8), 0, stream>>>(Wk, wkT);
  transpose_cast_w<<<dim3(32, 32), dim3(32, 8), 0, stream>>>(Wv, wvT);
  hipMemsetAsync(rs, 0, (size_t)BATCH * SEQ * 4, stream);

  // Q = xb·Wq, K = xb·Wk  (M=16384, N=1024, K=1024)
  gemm_bt<0><<<dim3(8, 128, 1), 256, 0, stream>>>(xb, 0, DIM, wqT, 0, DIM, qb, 0, DIM,
                                                  DIM, 1.f, nullptr);
  gemm_bt<0><<<dim3(8, 128, 1), 256, 0, stream>>>(xb, 0, DIM, wkT, 0, DIM, kb, 0, DIM,
                                                  DIM, 1.f, nullptr);
  // Vt[b][d][n] = (xb·Wv)[b*2048+n][d]
  gemm_bt<1><<<dim3(8, 128, 1), 256, 0, stream>>>(xb, 0, DIM, wvT, 0, DIM, vt,
                                                  (size_t)DIM * SEQ, SEQ, DIM, 1.f,
                                                  nullptr);
  // E = exp(scale·Q·K^T), causal, bf16, lower tiles only; rowsum via epilogue atomics
  gemm_bt<2><<<dim3(16, 16, BATCH), 256, 0, stream>>>(
      qb, (size_t)SEQ * DIM, DIM, kb, (size_t)SEQ * DIM, DIM, eb, (size_t)SEQ * SEQ, SEQ,
      DIM, 0.03125f, rs);
  // out = (E·V) / rowsum via Vt, K-loop causally limited, heavy blocks first
  gemm_bt<3><<<dim3(8, 16, BATCH), 256, 0, stream>>>(
      eb, (size_t)SEQ * SEQ, SEQ, vt, (size_t)DIM * SEQ, SEQ, out, (size_t)SEQ * DIM, DIM,
      SEQ, 1.f, rs);
}